// Round 8
// baseline (297.772 us; speedup 1.0000x reference)
//
#include <hip/hip_runtime.h>

// ---------------------------------------------------------------------------
// 2-layer GCN + global mean pool, MI355X (gfx950).
//   A_hat = D^{-1/2}(A+I)D^{-1/2}
//   G' = dinv*(X @ W1) fp16;  H'' = dinv*relu(dinv*A_sum(G') + b1) fp16
//   out = pool(dinv*A_sum(H'')) @ W2 + b2
// R8: (1) aggs use 16-lane groups (uint4 = 256B fp16 row per request; 4 nodes
//     in flight per wave + unroll2 = 8 request streams/wave, was 2) - attacks
//     the latency-bound profile (VALUBusy 20%, HBM 20%);
//     (2) dispatches 13 -> 8: one memset, dinv folded into block_scan,
//     finalize self-scans bsum, gemm fused with fill (independent work).
// ---------------------------------------------------------------------------

#define D 128
#define NGRAPH 64
#define SCAN_B 1024
#define A1_BLOCKS 1024   // 16384 16-lane groups
#define A2_BLOCKS 768    // 12288 groups (fewer pool-flush atomics)

typedef _Float16 h16x2 __attribute__((ext_vector_type(2)));

__device__ __forceinline__ float2 h2f(unsigned u) {
    h16x2 h = __builtin_bit_cast(h16x2, u);
    return make_float2((float)h.x, (float)h.y);
}
__device__ __forceinline__ unsigned f2h(float x, float y) {
    h16x2 h;
    h.x = (_Float16)x;
    h.y = (_Float16)y;
    return __builtin_bit_cast(unsigned, h);
}
__device__ __forceinline__ void acc8(uint4 u, float* a) {
    float2 t;
    t = h2f(u.x); a[0] += t.x; a[1] += t.y;
    t = h2f(u.y); a[2] += t.x; a[3] += t.y;
    t = h2f(u.z); a[4] += t.x; a[5] += t.y;
    t = h2f(u.w); a[6] += t.x; a[7] += t.y;
}

// --- diagnostic: all-zero output (ws too small) ----------------------------
__global__ void zero_out_kernel(float* __restrict__ out, int n) {
    int i = blockIdx.x * blockDim.x + threadIdx.x;
    if (i < n) out[i] = 0.f;
}

// --- CSR build -------------------------------------------------------------
__global__ void count_kernel(const int* __restrict__ ei, int* __restrict__ deg,
                             int E, int N) {
    int e = blockIdx.x * blockDim.x + threadIdx.x;
    if (e < E) {
        int d = ei[E + e];
        if (d >= 0 && d < N) atomicAdd(&deg[d], 1);
    }
}

// per-block scan of deg -> local exclusive prefix; also emits dinv.
__global__ __launch_bounds__(SCAN_B) void block_scan_kernel(const int* __restrict__ deg,
                                                            int* __restrict__ rowstart,
                                                            int* __restrict__ bsum,
                                                            float* __restrict__ dinv,
                                                            int N) {
    __shared__ int sc[SCAN_B];
    int t = threadIdx.x;
    int i = blockIdx.x * SCAN_B + t;
    int orig = (i < N) ? deg[i] : 0;
    int v = orig;
    sc[t] = v;
    __syncthreads();
    for (int off = 1; off < SCAN_B; off <<= 1) {
        int add = (t >= off) ? sc[t - off] : 0;
        __syncthreads();
        v += add;
        sc[t] = v;
        __syncthreads();
    }
    if (i < N) {
        rowstart[i] = v - orig;                      // local exclusive
        dinv[i]     = rsqrtf((float)orig + 1.0f);    // +1 self loop
    }
    if (t == SCAN_B - 1) bsum[blockIdx.x] = v;
}

// each block self-computes its bsum prefix (nblk<=64) -> no scan_sums kernel.
__global__ __launch_bounds__(SCAN_B) void finalize_scan_kernel(const int* __restrict__ bsum,
                                                               int* __restrict__ rowstart,
                                                               int* __restrict__ cursor,
                                                               int N, int nblk, int E) {
    __shared__ int s_off;
    if (threadIdx.x < 64) {
        int lane = (int)threadIdx.x;
        int v = (lane < nblk && lane < (int)blockIdx.x) ? bsum[lane] : 0;
        for (int off = 32; off > 0; off >>= 1) v += __shfl_down(v, off);
        if (lane == 0) s_off = v;
    }
    __syncthreads();
    int i = blockIdx.x * SCAN_B + threadIdx.x;
    if (i < N) {
        int rs = rowstart[i] + s_off;
        rowstart[i] = rs;
        cursor[i]   = rs;
    }
    if (blockIdx.x == 0 && threadIdx.x == 0) rowstart[N] = E;
}

// --- Fused GEMM + fill ------------------------------------------------------
// Blocks [0,gb): G' = dinv*(X @ W1) -> fp16.  Blocks [gb,gb+eb): CSR fill.
// Independent work overlapped in one dispatch.
__global__ __launch_bounds__(256) void gemm_fill_kernel(const float* __restrict__ X,
                                                        const float* __restrict__ W,
                                                        const float* __restrict__ dinv,
                                                        unsigned* __restrict__ Gh,
                                                        const int* __restrict__ ei,
                                                        int* __restrict__ cursor,
                                                        int* __restrict__ colidx,
                                                        int N, int E, int gb) {
    __shared__ float Alds[64][D];
    if ((int)blockIdx.x >= gb) {
        int e = ((int)blockIdx.x - gb) * 256 + (int)threadIdx.x;
        if (e < E) {
            int d = ei[E + e];
            if (d >= 0 && d < N) {
                int slot = atomicAdd(&cursor[d], 1);
                if (slot >= 0 && slot < E) {
                    int s = ei[e];
                    colidx[slot] = min(max(s, 0), N - 1);
                }
            }
        }
        return;
    }

    int t = threadIdx.x;
    int row0 = blockIdx.x * 64;
    {
        int c4 = (t & 31) * 4;
        int rsub = t >> 5;
#pragma unroll
        for (int rr = 0; rr < 8; ++rr) {
            int r = rr * 8 + rsub;
            int row = row0 + r;
            if (row >= N) row = N - 1;
            float4 v = *(const float4*)(X + (size_t)row * D + c4);
            *(float4*)&Alds[r][c4] = v;
        }
    }
    __syncthreads();

    int tx = t & 31, ty = t >> 5;
    float4 acc[8];
#pragma unroll
    for (int r = 0; r < 8; ++r) acc[r] = make_float4(0.f, 0.f, 0.f, 0.f);

    for (int k = 0; k < D; ++k) {
        float4 w = *(const float4*)(W + (size_t)k * D + tx * 4);
#pragma unroll
        for (int r = 0; r < 8; ++r) {
            float a = Alds[ty * 8 + r][k];
            acc[r].x = fmaf(a, w.x, acc[r].x);
            acc[r].y = fmaf(a, w.y, acc[r].y);
            acc[r].z = fmaf(a, w.z, acc[r].z);
            acc[r].w = fmaf(a, w.w, acc[r].w);
        }
    }

#pragma unroll
    for (int r = 0; r < 8; ++r) {
        int row = row0 + ty * 8 + r;
        if (row < N) {
            float dv = dinv[row];
            uint2 o;
            o.x = f2h(dv * acc[r].x, dv * acc[r].y);
            o.y = f2h(dv * acc[r].z, dv * acc[r].w);
            *(uint2*)(Gh + (size_t)row * (D / 2) + tx * 2) = o;
        }
    }
}

// --- agg1: H''_i = dinv_i * relu(dinv_i*(sum_e G'_s + G'_i) + b1), fp16 -----
// 16-lane group per node: uint4/lane covers the 256B row in ONE request;
// 4 nodes concurrently per wave + unroll2 = 8 outstanding gathers/wave.
__global__ __launch_bounds__(256) void agg1_kernel(const uint4* __restrict__ Ghq,
                                                   const int* __restrict__ rowstart,
                                                   const int* __restrict__ colidx,
                                                   const float* __restrict__ dinv,
                                                   const float* __restrict__ b1,
                                                   uint4* __restrict__ Hhq,
                                                   int N, int chunk) {
    int gid = blockIdx.x * 16 + (threadIdx.x >> 4);
    int l   = threadIdx.x & 15;
    int i0 = gid * chunk, i1 = min(i0 + chunk, N);
    float4 bA = *(const float4*)(b1 + 8 * l);
    float4 bB = *(const float4*)(b1 + 8 * l + 4);
    for (int i = i0; i < i1; ++i) {
        float di = dinv[i];
        float a[8] = {0.f, 0.f, 0.f, 0.f, 0.f, 0.f, 0.f, 0.f};
        acc8(Ghq[(size_t)i * 16 + l], a);                  // self term
        int e0 = rowstart[i], e1 = rowstart[i + 1];
        int e = e0;
        if ((e1 - e0) & 1) {
            acc8(Ghq[(size_t)colidx[e] * 16 + l], a);
            ++e;
        }
        for (; e < e1; e += 2) {
            uint4 v0 = Ghq[(size_t)colidx[e] * 16 + l];
            uint4 v1 = Ghq[(size_t)colidx[e + 1] * 16 + l];
            acc8(v0, a);
            acc8(v1, a);
        }
        float h0 = fmaxf(fmaf(di, a[0], bA.x), 0.f) * di;
        float h1 = fmaxf(fmaf(di, a[1], bA.y), 0.f) * di;
        float h2 = fmaxf(fmaf(di, a[2], bA.z), 0.f) * di;
        float h3 = fmaxf(fmaf(di, a[3], bA.w), 0.f) * di;
        float h4 = fmaxf(fmaf(di, a[4], bB.x), 0.f) * di;
        float h5 = fmaxf(fmaf(di, a[5], bB.y), 0.f) * di;
        float h6 = fmaxf(fmaf(di, a[6], bB.z), 0.f) * di;
        float h7 = fmaxf(fmaf(di, a[7], bB.w), 0.f) * di;
        uint4 o;
        o.x = f2h(h0, h1);
        o.y = f2h(h2, h3);
        o.z = f2h(h4, h5);
        o.w = f2h(h6, h7);
        Hhq[(size_t)i * 16 + l] = o;
    }
}

// --- agg2 + pool: pool[batch_i] += dinv_i*(sum_e H''_s + H''_i) -------------
__global__ __launch_bounds__(256) void agg2_pool_kernel(const uint4* __restrict__ Hhq,
                                                        const int* __restrict__ rowstart,
                                                        const int* __restrict__ colidx,
                                                        const float* __restrict__ dinv,
                                                        const int* __restrict__ batch,
                                                        float* __restrict__ pool,
                                                        int N, int chunk) {
    int gid = blockIdx.x * 16 + (threadIdx.x >> 4);
    int l   = threadIdx.x & 15;
    int i0 = gid * chunk, i1 = min(i0 + chunk, N);
    if (i0 >= N) return;

    float pa[8] = {0.f, 0.f, 0.f, 0.f, 0.f, 0.f, 0.f, 0.f};
    int cur = min(max(batch[i0], 0), NGRAPH - 1);
    for (int i = i0; i < i1; ++i) {
        float di = dinv[i];
        float a[8] = {0.f, 0.f, 0.f, 0.f, 0.f, 0.f, 0.f, 0.f};
        acc8(Hhq[(size_t)i * 16 + l], a);                  // self term
        int e0 = rowstart[i], e1 = rowstart[i + 1];
        int e = e0;
        if ((e1 - e0) & 1) {
            acc8(Hhq[(size_t)colidx[e] * 16 + l], a);
            ++e;
        }
        for (; e < e1; e += 2) {
            uint4 v0 = Hhq[(size_t)colidx[e] * 16 + l];
            uint4 v1 = Hhq[(size_t)colidx[e + 1] * 16 + l];
            acc8(v0, a);
            acc8(v1, a);
        }
        int b = min(max(batch[i], 0), NGRAPH - 1);
        if (b != cur) {
#pragma unroll
            for (int j = 0; j < 8; ++j) {
                atomicAdd(&pool[(size_t)cur * D + 8 * l + j], pa[j]);
                pa[j] = 0.f;
            }
            cur = b;
        }
#pragma unroll
        for (int j = 0; j < 8; ++j) pa[j] = fmaf(di, a[j], pa[j]);
    }
#pragma unroll
    for (int j = 0; j < 8; ++j)
        atomicAdd(&pool[(size_t)cur * D + 8 * l + j], pa[j]);
}

// --- Final tiny GEMM: out[g][o] = (pool[g]/cnt_g) . W2[:,o] + b2[o] ---------
__device__ __forceinline__ int lbound(const int* __restrict__ a, int n, int v) {
    int lo = 0, hi = n;
    while (lo < hi) {
        int m = (lo + hi) >> 1;
        if (a[m] < v) lo = m + 1; else hi = m;
    }
    return lo;
}

__global__ void final_gemm_kernel(const float* __restrict__ pool,
                                  const int* __restrict__ batch,
                                  const float* __restrict__ W2,
                                  const float* __restrict__ b2,
                                  float* __restrict__ out, int N) {
    int g = blockIdx.x, o = threadIdx.x;
    int s = lbound(batch, N, g);
    int e = lbound(batch, N, g + 1);
    float inv_cnt = 1.0f / fmaxf((float)(e - s), 1.0f);
    float acc = 0.f;
#pragma unroll 4
    for (int k = 0; k < D; ++k)
        acc = fmaf(pool[g * D + k], W2[k * D + o], acc);
    out[g * D + o] = acc * inv_cnt + b2[o];
}

// ---------------------------------------------------------------------------

extern "C" void kernel_launch(void* const* d_in, const int* in_sizes, int n_in,
                              void* d_out, int out_size, void* d_ws, size_t ws_size,
                              hipStream_t stream) {
    const float* x     = (const float*)d_in[0];
    const int*   ei    = (const int*)  d_in[1];
    const int*   batch = (const int*)  d_in[2];
    const float* W1    = (const float*)d_in[3];
    const float* b1    = (const float*)d_in[4];
    const float* W2    = (const float*)d_in[5];
    const float* b2    = (const float*)d_in[6];
    float* out = (float*)d_out;

    const int N = in_sizes[0] / D;
    const int E = in_sizes[1] / 2;
    const int nblk = (N + SCAN_B - 1) / SCAN_B;   // <=64 for N<=65536

    // workspace carve-up (256B aligned); deg+pool adjacent -> single memset
    char* ws = (char*)d_ws;
    size_t off = 0;
    auto carve = [&](size_t bytes) {
        size_t o = off;
        off = (off + bytes + 255) & ~(size_t)255;
        return o;
    };
    size_t o_deg      = carve((size_t)N * 4);
    size_t o_pool     = carve((size_t)NGRAPH * D * 4);
    size_t zspan      = off;                       // memset [0, zspan)
    size_t o_rowstart = carve((size_t)(N + 1) * 4);
    size_t o_cursor   = carve((size_t)(N + 1) * 4);
    size_t o_dinv     = carve((size_t)N * 4);
    size_t o_colidx   = carve((size_t)E * 4);
    size_t o_bsum     = carve((size_t)64 * 4);
    size_t o_gh       = carve((size_t)N * D * 2);  // fp16 G'
    size_t o_hh       = carve((size_t)N * D * 2);  // fp16 H''
    size_t need = off;

    if (ws_size < need) {
        zero_out_kernel<<<(out_size + 255) / 256, 256, 0, stream>>>(out, out_size);
        return;
    }

    int*      deg      = (int*)     (ws + o_deg);
    float*    pool     = (float*)   (ws + o_pool);
    int*      rowstart = (int*)     (ws + o_rowstart);
    int*      cursor   = (int*)     (ws + o_cursor);
    float*    dinv     = (float*)   (ws + o_dinv);
    int*      colidx   = (int*)     (ws + o_colidx);
    int*      bsum     = (int*)     (ws + o_bsum);
    unsigned* Gh       = (unsigned*)(ws + o_gh);
    unsigned* Hh       = (unsigned*)(ws + o_hh);

    hipMemsetAsync(ws, 0, zspan, stream);          // deg + pool in one shot

    int eb = (E + 255) / 256;
    int gb = (N + 63) / 64;
    count_kernel<<<eb, 256, 0, stream>>>(ei, deg, E, N);
    block_scan_kernel<<<nblk, SCAN_B, 0, stream>>>(deg, rowstart, bsum, dinv, N);
    finalize_scan_kernel<<<nblk, SCAN_B, 0, stream>>>(bsum, rowstart, cursor, N, nblk, E);
    // fused: G' GEMM (blocks [0,gb)) + CSR fill (blocks [gb,gb+eb))
    gemm_fill_kernel<<<gb + eb, 256, 0, stream>>>(x, W1, dinv, Gh, ei, cursor,
                                                  colidx, N, E, gb);

    int chunk1 = (N + A1_BLOCKS * 16 - 1) / (A1_BLOCKS * 16);
    int chunk2 = (N + A2_BLOCKS * 16 - 1) / (A2_BLOCKS * 16);
    agg1_kernel<<<A1_BLOCKS, 256, 0, stream>>>((const uint4*)Gh, rowstart, colidx,
                                               dinv, b1, (uint4*)Hh, N, chunk1);
    agg2_pool_kernel<<<A2_BLOCKS, 256, 0, stream>>>((const uint4*)Hh, rowstart, colidx,
                                                    dinv, batch, pool, N, chunk2);
    final_gemm_kernel<<<NGRAPH, D, 0, stream>>>(pool, batch, W2, b2, out, N);
}

// Round 9
// 242.151 us; speedup vs baseline: 1.2297x; 1.2297x over previous
//
#include <hip/hip_runtime.h>

// ---------------------------------------------------------------------------
// 2-layer GCN + global mean pool, MI355X (gfx950).
//   A_hat = D^{-1/2}(A+I)D^{-1/2}
//   G' = dinv*(X @ W1) fp16;  H'' = dinv*relu(dinv*A_sum(G') + b1) fp16
//   out = pool(dinv*A_sum(H'')) @ W2 + b2
// R9: revert R8's 16-lane agg groups (intra-wave divergence on edge-loop trip
// counts -> 100us, VALUBusy 6%). Back to 64-lane wave-per-node (uniform loop)
// with UNROLL-4 edge loop for 4 outstanding 256B row gathers per wave.
// Keep R8's dispatch fusions (1 memset, dinv in scan, fused gemm+fill).
// ---------------------------------------------------------------------------

#define D 128
#define NGRAPH 64
#define SCAN_B 1024
#define AGG_BLOCKS 2048   // 8192 waves = 32/CU

typedef _Float16 h16x2 __attribute__((ext_vector_type(2)));

__device__ __forceinline__ float2 h2f(unsigned u) {
    h16x2 h = __builtin_bit_cast(h16x2, u);
    return make_float2((float)h.x, (float)h.y);
}
__device__ __forceinline__ unsigned f2h(float x, float y) {
    h16x2 h;
    h.x = (_Float16)x;
    h.y = (_Float16)y;
    return __builtin_bit_cast(unsigned, h);
}

// --- diagnostic: all-zero output (ws too small) ----------------------------
__global__ void zero_out_kernel(float* __restrict__ out, int n) {
    int i = blockIdx.x * blockDim.x + threadIdx.x;
    if (i < n) out[i] = 0.f;
}

// --- CSR build -------------------------------------------------------------
__global__ void count_kernel(const int* __restrict__ ei, int* __restrict__ deg,
                             int E, int N) {
    int e = blockIdx.x * blockDim.x + threadIdx.x;
    if (e < E) {
        int d = ei[E + e];
        if (d >= 0 && d < N) atomicAdd(&deg[d], 1);
    }
}

// per-block scan of deg -> local exclusive prefix; also emits dinv.
__global__ __launch_bounds__(SCAN_B) void block_scan_kernel(const int* __restrict__ deg,
                                                            int* __restrict__ rowstart,
                                                            int* __restrict__ bsum,
                                                            float* __restrict__ dinv,
                                                            int N) {
    __shared__ int sc[SCAN_B];
    int t = threadIdx.x;
    int i = blockIdx.x * SCAN_B + t;
    int orig = (i < N) ? deg[i] : 0;
    int v = orig;
    sc[t] = v;
    __syncthreads();
    for (int off = 1; off < SCAN_B; off <<= 1) {
        int add = (t >= off) ? sc[t - off] : 0;
        __syncthreads();
        v += add;
        sc[t] = v;
        __syncthreads();
    }
    if (i < N) {
        rowstart[i] = v - orig;                      // local exclusive
        dinv[i]     = rsqrtf((float)orig + 1.0f);    // +1 self loop
    }
    if (t == SCAN_B - 1) bsum[blockIdx.x] = v;
}

// each block self-computes its bsum prefix (nblk<=64) -> no scan_sums kernel.
__global__ __launch_bounds__(SCAN_B) void finalize_scan_kernel(const int* __restrict__ bsum,
                                                               int* __restrict__ rowstart,
                                                               int* __restrict__ cursor,
                                                               int N, int nblk, int E) {
    __shared__ int s_off;
    if (threadIdx.x < 64) {
        int lane = (int)threadIdx.x;
        int v = (lane < nblk && lane < (int)blockIdx.x) ? bsum[lane] : 0;
        for (int off = 32; off > 0; off >>= 1) v += __shfl_down(v, off);
        if (lane == 0) s_off = v;
    }
    __syncthreads();
    int i = blockIdx.x * SCAN_B + threadIdx.x;
    if (i < N) {
        int rs = rowstart[i] + s_off;
        rowstart[i] = rs;
        cursor[i]   = rs;
    }
    if (blockIdx.x == 0 && threadIdx.x == 0) rowstart[N] = E;
}

// --- Fused GEMM + fill ------------------------------------------------------
// Blocks [0,gb): G' = dinv*(X @ W1) -> fp16.  Blocks [gb,gb+eb): CSR fill.
__global__ __launch_bounds__(256) void gemm_fill_kernel(const float* __restrict__ X,
                                                        const float* __restrict__ W,
                                                        const float* __restrict__ dinv,
                                                        unsigned* __restrict__ Gh,
                                                        const int* __restrict__ ei,
                                                        int* __restrict__ cursor,
                                                        int* __restrict__ colidx,
                                                        int N, int E, int gb) {
    __shared__ float Alds[64][D];
    if ((int)blockIdx.x >= gb) {
        int e = ((int)blockIdx.x - gb) * 256 + (int)threadIdx.x;
        if (e < E) {
            int d = ei[E + e];
            if (d >= 0 && d < N) {
                int slot = atomicAdd(&cursor[d], 1);
                if (slot >= 0 && slot < E) {
                    int s = ei[e];
                    colidx[slot] = min(max(s, 0), N - 1);
                }
            }
        }
        return;
    }

    int t = threadIdx.x;
    int row0 = blockIdx.x * 64;
    {
        int c4 = (t & 31) * 4;
        int rsub = t >> 5;
#pragma unroll
        for (int rr = 0; rr < 8; ++rr) {
            int r = rr * 8 + rsub;
            int row = row0 + r;
            if (row >= N) row = N - 1;
            float4 v = *(const float4*)(X + (size_t)row * D + c4);
            *(float4*)&Alds[r][c4] = v;
        }
    }
    __syncthreads();

    int tx = t & 31, ty = t >> 5;
    float4 acc[8];
#pragma unroll
    for (int r = 0; r < 8; ++r) acc[r] = make_float4(0.f, 0.f, 0.f, 0.f);

    for (int k = 0; k < D; ++k) {
        float4 w = *(const float4*)(W + (size_t)k * D + tx * 4);
#pragma unroll
        for (int r = 0; r < 8; ++r) {
            float a = Alds[ty * 8 + r][k];
            acc[r].x = fmaf(a, w.x, acc[r].x);
            acc[r].y = fmaf(a, w.y, acc[r].y);
            acc[r].z = fmaf(a, w.z, acc[r].z);
            acc[r].w = fmaf(a, w.w, acc[r].w);
        }
    }

#pragma unroll
    for (int r = 0; r < 8; ++r) {
        int row = row0 + ty * 8 + r;
        if (row < N) {
            float dv = dinv[row];
            uint2 o;
            o.x = f2h(dv * acc[r].x, dv * acc[r].y);
            o.y = f2h(dv * acc[r].z, dv * acc[r].w);
            *(uint2*)(Gh + (size_t)row * (D / 2) + tx * 2) = o;
        }
    }
}

// --- agg1: H''_i = dinv_i * relu(dinv_i*(sum_e G'_s + G'_i) + b1), fp16 -----
// 64-lane wave per node (uniform edge loop), 4B/lane = one 256B row request
// per edge; UNROLL-4 => 4 outstanding gathers per wave.
__global__ __launch_bounds__(256) void agg1_kernel(const unsigned* __restrict__ Gh,
                                                   const int* __restrict__ rowstart,
                                                   const int* __restrict__ colidx,
                                                   const float* __restrict__ dinv,
                                                   const float* __restrict__ b1,
                                                   unsigned* __restrict__ Hh,
                                                   int N, int chunk) {
    int gid  = blockIdx.x * 4 + (threadIdx.x >> 6);
    int lane = threadIdx.x & 63;
    int i0 = gid * chunk, i1 = min(i0 + chunk, N);
    float bx = b1[2 * lane], by = b1[2 * lane + 1];
    for (int i = i0; i < i1; ++i) {
        float di = dinv[i];
        float2 acc = h2f(Gh[(size_t)i * (D / 2) + lane]);   // self term
        int e0 = rowstart[i], e1 = rowstart[i + 1];
        int e = e0;
        for (; e + 3 < e1; e += 4) {
            int s0 = colidx[e], s1 = colidx[e + 1];
            int s2 = colidx[e + 2], s3 = colidx[e + 3];
            unsigned u0 = Gh[(size_t)s0 * (D / 2) + lane];
            unsigned u1 = Gh[(size_t)s1 * (D / 2) + lane];
            unsigned u2 = Gh[(size_t)s2 * (D / 2) + lane];
            unsigned u3 = Gh[(size_t)s3 * (D / 2) + lane];
            float2 v0 = h2f(u0), v1 = h2f(u1), v2 = h2f(u2), v3 = h2f(u3);
            acc.x += (v0.x + v1.x) + (v2.x + v3.x);
            acc.y += (v0.y + v1.y) + (v2.y + v3.y);
        }
        for (; e < e1; ++e) {
            float2 v = h2f(Gh[(size_t)colidx[e] * (D / 2) + lane]);
            acc.x += v.x;
            acc.y += v.y;
        }
        float hx = fmaxf(fmaf(di, acc.x, bx), 0.f) * di;    // H'' = dinv*relu
        float hy = fmaxf(fmaf(di, acc.y, by), 0.f) * di;
        Hh[(size_t)i * (D / 2) + lane] = f2h(hx, hy);
    }
}

// --- agg2 + pool: pool[batch_i] += dinv_i*(sum_e H''_s + H''_i) -------------
__global__ __launch_bounds__(256) void agg2_pool_kernel(const unsigned* __restrict__ Hh,
                                                        const int* __restrict__ rowstart,
                                                        const int* __restrict__ colidx,
                                                        const float* __restrict__ dinv,
                                                        const int* __restrict__ batch,
                                                        float* __restrict__ pool,
                                                        int N, int chunk) {
    int gid  = blockIdx.x * 4 + (threadIdx.x >> 6);
    int lane = threadIdx.x & 63;
    int i0 = gid * chunk, i1 = min(i0 + chunk, N);
    if (i0 >= N) return;

    float2 pa = make_float2(0.f, 0.f);
    int cur = min(max(batch[i0], 0), NGRAPH - 1);
    for (int i = i0; i < i1; ++i) {
        float di = dinv[i];
        float2 a = h2f(Hh[(size_t)i * (D / 2) + lane]);     // self term
        int e0 = rowstart[i], e1 = rowstart[i + 1];
        int e = e0;
        for (; e + 3 < e1; e += 4) {
            int s0 = colidx[e], s1 = colidx[e + 1];
            int s2 = colidx[e + 2], s3 = colidx[e + 3];
            unsigned u0 = Hh[(size_t)s0 * (D / 2) + lane];
            unsigned u1 = Hh[(size_t)s1 * (D / 2) + lane];
            unsigned u2 = Hh[(size_t)s2 * (D / 2) + lane];
            unsigned u3 = Hh[(size_t)s3 * (D / 2) + lane];
            float2 v0 = h2f(u0), v1 = h2f(u1), v2 = h2f(u2), v3 = h2f(u3);
            a.x += (v0.x + v1.x) + (v2.x + v3.x);
            a.y += (v0.y + v1.y) + (v2.y + v3.y);
        }
        for (; e < e1; ++e) {
            float2 v = h2f(Hh[(size_t)colidx[e] * (D / 2) + lane]);
            a.x += v.x;
            a.y += v.y;
        }
        int b = min(max(batch[i], 0), NGRAPH - 1);
        if (b != cur) {
            atomicAdd(&pool[(size_t)cur * D + 2 * lane], pa.x);
            atomicAdd(&pool[(size_t)cur * D + 2 * lane + 1], pa.y);
            pa = make_float2(0.f, 0.f);
            cur = b;
        }
        pa.x = fmaf(di, a.x, pa.x);
        pa.y = fmaf(di, a.y, pa.y);
    }
    atomicAdd(&pool[(size_t)cur * D + 2 * lane], pa.x);
    atomicAdd(&pool[(size_t)cur * D + 2 * lane + 1], pa.y);
}

// --- Final tiny GEMM: out[g][o] = (pool[g]/cnt_g) . W2[:,o] + b2[o] ---------
__device__ __forceinline__ int lbound(const int* __restrict__ a, int n, int v) {
    int lo = 0, hi = n;
    while (lo < hi) {
        int m = (lo + hi) >> 1;
        if (a[m] < v) lo = m + 1; else hi = m;
    }
    return lo;
}

__global__ void final_gemm_kernel(const float* __restrict__ pool,
                                  const int* __restrict__ batch,
                                  const float* __restrict__ W2,
                                  const float* __restrict__ b2,
                                  float* __restrict__ out, int N) {
    int g = blockIdx.x, o = threadIdx.x;
    int s = lbound(batch, N, g);
    int e = lbound(batch, N, g + 1);
    float inv_cnt = 1.0f / fmaxf((float)(e - s), 1.0f);
    float acc = 0.f;
#pragma unroll 4
    for (int k = 0; k < D; ++k)
        acc = fmaf(pool[g * D + k], W2[k * D + o], acc);
    out[g * D + o] = acc * inv_cnt + b2[o];
}

// ---------------------------------------------------------------------------

extern "C" void kernel_launch(void* const* d_in, const int* in_sizes, int n_in,
                              void* d_out, int out_size, void* d_ws, size_t ws_size,
                              hipStream_t stream) {
    const float* x     = (const float*)d_in[0];
    const int*   ei    = (const int*)  d_in[1];
    const int*   batch = (const int*)  d_in[2];
    const float* W1    = (const float*)d_in[3];
    const float* b1    = (const float*)d_in[4];
    const float* W2    = (const float*)d_in[5];
    const float* b2    = (const float*)d_in[6];
    float* out = (float*)d_out;

    const int N = in_sizes[0] / D;
    const int E = in_sizes[1] / 2;
    const int nblk = (N + SCAN_B - 1) / SCAN_B;   // <=64 for N<=65536

    // workspace carve-up (256B aligned); deg+pool adjacent -> single memset
    char* ws = (char*)d_ws;
    size_t off = 0;
    auto carve = [&](size_t bytes) {
        size_t o = off;
        off = (off + bytes + 255) & ~(size_t)255;
        return o;
    };
    size_t o_deg      = carve((size_t)N * 4);
    size_t o_pool     = carve((size_t)NGRAPH * D * 4);
    size_t zspan      = off;                       // memset [0, zspan)
    size_t o_rowstart = carve((size_t)(N + 1) * 4);
    size_t o_cursor   = carve((size_t)(N + 1) * 4);
    size_t o_dinv     = carve((size_t)N * 4);
    size_t o_colidx   = carve((size_t)E * 4);
    size_t o_bsum     = carve((size_t)64 * 4);
    size_t o_gh       = carve((size_t)N * D * 2);  // fp16 G'
    size_t o_hh       = carve((size_t)N * D * 2);  // fp16 H''
    size_t need = off;

    if (ws_size < need) {
        zero_out_kernel<<<(out_size + 255) / 256, 256, 0, stream>>>(out, out_size);
        return;
    }

    int*      deg      = (int*)     (ws + o_deg);
    float*    pool     = (float*)   (ws + o_pool);
    int*      rowstart = (int*)     (ws + o_rowstart);
    int*      cursor   = (int*)     (ws + o_cursor);
    float*    dinv     = (float*)   (ws + o_dinv);
    int*      colidx   = (int*)     (ws + o_colidx);
    int*      bsum     = (int*)     (ws + o_bsum);
    unsigned* Gh       = (unsigned*)(ws + o_gh);
    unsigned* Hh       = (unsigned*)(ws + o_hh);

    hipMemsetAsync(ws, 0, zspan, stream);          // deg + pool in one shot

    int eb = (E + 255) / 256;
    int gb = (N + 63) / 64;
    count_kernel<<<eb, 256, 0, stream>>>(ei, deg, E, N);
    block_scan_kernel<<<nblk, SCAN_B, 0, stream>>>(deg, rowstart, bsum, dinv, N);
    finalize_scan_kernel<<<nblk, SCAN_B, 0, stream>>>(bsum, rowstart, cursor, N, nblk, E);
    gemm_fill_kernel<<<gb + eb, 256, 0, stream>>>(x, W1, dinv, Gh, ei, cursor,
                                                  colidx, N, E, gb);

    int groups = AGG_BLOCKS * 4;
    int chunk  = (N + groups - 1) / groups;
    agg1_kernel<<<AGG_BLOCKS, 256, 0, stream>>>(Gh, rowstart, colidx, dinv, b1,
                                                Hh, N, chunk);
    agg2_pool_kernel<<<AGG_BLOCKS, 256, 0, stream>>>(Hh, rowstart, colidx, dinv,
                                                     batch, pool, N, chunk);
    final_gemm_kernel<<<NGRAPH, D, 0, stream>>>(pool, batch, W2, b2, out, N);
}

// Round 10
// 224.201 us; speedup vs baseline: 1.3281x; 1.0801x over previous
//
#include <hip/hip_runtime.h>

// ---------------------------------------------------------------------------
// 2-layer GCN + global mean pool, MI355X (gfx950).
//   A_hat = D^{-1/2}(A+I)D^{-1/2}
//   G' = dinv*(X @ W1) fp16 [MFMA fp16];  H'' = dinv*relu(dinv*A_sum(G')+b1)
//   out = pool(dinv*A_sum(H'')) @ W2 + b2
// R10: (1) X@W1 moves to v_mfma_f32_16x16x32_f16 (was fp32 VALU, ~30us @
//     VALUBusy 26%); X,W1 converted to fp16 in the count dispatch;
//     (2) agg edge loops unroll 4 -> 8 (more outstanding 256B gathers).
// ws_size is 256 MiB (harness poison-fill showed 268MB); we use ~42 MB.
// ---------------------------------------------------------------------------

#define D 128
#define NGRAPH 64
#define SCAN_B 1024
#define AGG_BLOCKS 2048   // 8192 waves = 32/CU

typedef _Float16 h16x2 __attribute__((ext_vector_type(2)));
typedef _Float16 f16x8 __attribute__((ext_vector_type(8)));
typedef float    f32x4 __attribute__((ext_vector_type(4)));

__device__ __forceinline__ float2 h2f(unsigned u) {
    h16x2 h = __builtin_bit_cast(h16x2, u);
    return make_float2((float)h.x, (float)h.y);
}
__device__ __forceinline__ unsigned f2h(float x, float y) {
    h16x2 h;
    h.x = (_Float16)x;
    h.y = (_Float16)y;
    return __builtin_bit_cast(unsigned, h);
}

// --- diagnostic: all-zero output (ws too small) ----------------------------
__global__ void zero_out_kernel(float* __restrict__ out, int n) {
    int i = blockIdx.x * blockDim.x + threadIdx.x;
    if (i < n) out[i] = 0.f;
}

// --- Fused: X->fp16 conversion | W1->fp16 MFMA-B pack | degree count -------
// Blocks [0,cb): convert X (float4 -> 4 halves). [cb,cb+8): pack WB.
// [cb+8, cb+8+eb): count dst degrees.
__global__ __launch_bounds__(256) void conv_count_kernel(const float* __restrict__ X,
                                                         _Float16* __restrict__ Xh,
                                                         const float* __restrict__ W1,
                                                         _Float16* __restrict__ WB,
                                                         const int* __restrict__ ei,
                                                         int* __restrict__ deg,
                                                         int N, int E, int cb) {
    int b = (int)blockIdx.x;
    if (b < cb) {
        int idx = b * 256 + (int)threadIdx.x;     // float4 index
        int total = N * (D / 4);
        if (idx < total) {
            float4 v = ((const float4*)X)[idx];
            uint2 o;
            o.x = f2h(v.x, v.y);
            o.y = f2h(v.z, v.w);
            ((uint2*)Xh)[idx] = o;
        }
        return;
    }
    if (b < cb + 8) {
        // WB[((kt*8+nt)*64+lane)*8+j] = W1[(kt*32+(lane>>4)*8+j)*D + nt*16+(lane&15)]
        int idx = (b - cb) * 256 + (int)threadIdx.x;   // 0..2047
        int lane = idx & 63;
        int nt   = (idx >> 6) & 7;
        int kt   = idx >> 9;
        int col  = nt * 16 + (lane & 15);
        int krow = kt * 32 + (lane >> 4) * 8;
#pragma unroll
        for (int j = 0; j < 8; ++j)
            WB[idx * 8 + j] = (_Float16)W1[(krow + j) * D + col];
        return;
    }
    int e = (b - cb - 8) * 256 + (int)threadIdx.x;
    if (e < E) {
        int d = ei[E + e];
        if (d >= 0 && d < N) atomicAdd(&deg[d], 1);
    }
}

// per-block scan of deg -> local exclusive prefix; also emits dinv.
__global__ __launch_bounds__(SCAN_B) void block_scan_kernel(const int* __restrict__ deg,
                                                            int* __restrict__ rowstart,
                                                            int* __restrict__ bsum,
                                                            float* __restrict__ dinv,
                                                            int N) {
    __shared__ int sc[SCAN_B];
    int t = threadIdx.x;
    int i = blockIdx.x * SCAN_B + t;
    int orig = (i < N) ? deg[i] : 0;
    int v = orig;
    sc[t] = v;
    __syncthreads();
    for (int off = 1; off < SCAN_B; off <<= 1) {
        int add = (t >= off) ? sc[t - off] : 0;
        __syncthreads();
        v += add;
        sc[t] = v;
        __syncthreads();
    }
    if (i < N) {
        rowstart[i] = v - orig;                      // local exclusive
        dinv[i]     = rsqrtf((float)orig + 1.0f);    // +1 self loop
    }
    if (t == SCAN_B - 1) bsum[blockIdx.x] = v;
}

// each block self-computes its bsum prefix (nblk<=64) -> no scan_sums kernel.
__global__ __launch_bounds__(SCAN_B) void finalize_scan_kernel(const int* __restrict__ bsum,
                                                               int* __restrict__ rowstart,
                                                               int* __restrict__ cursor,
                                                               int N, int nblk, int E) {
    __shared__ int s_off;
    if (threadIdx.x < 64) {
        int lane = (int)threadIdx.x;
        int v = (lane < nblk && lane < (int)blockIdx.x) ? bsum[lane] : 0;
        for (int off = 32; off > 0; off >>= 1) v += __shfl_down(v, off);
        if (lane == 0) s_off = v;
    }
    __syncthreads();
    int i = blockIdx.x * SCAN_B + threadIdx.x;
    if (i < N) {
        int rs = rowstart[i] + s_off;
        rowstart[i] = rs;
        cursor[i]   = rs;
    }
    if (blockIdx.x == 0 && threadIdx.x == 0) rowstart[N] = E;
}

// --- Fused MFMA GEMM + fill -------------------------------------------------
// Blocks [0,gb): G' = dinv*(Xh @ W1h) via mfma_f32_16x16x32_f16, fp16 out.
// Blocks [gb,gb+eb): CSR fill.
__global__ __launch_bounds__(256) void gemm_fill_kernel(const _Float16* __restrict__ Xh,
                                                        const _Float16* __restrict__ WB,
                                                        const float* __restrict__ dinv,
                                                        _Float16* __restrict__ Gh,
                                                        const int* __restrict__ ei,
                                                        int* __restrict__ cursor,
                                                        int* __restrict__ colidx,
                                                        int N, int E, int gb) {
    if ((int)blockIdx.x >= gb) {
        int e = ((int)blockIdx.x - gb) * 256 + (int)threadIdx.x;
        if (e < E) {
            int d = ei[E + e];
            if (d >= 0 && d < N) {
                int slot = atomicAdd(&cursor[d], 1);
                if (slot >= 0 && slot < E) {
                    int s = ei[e];
                    colidx[slot] = min(max(s, 0), N - 1);
                }
            }
        }
        return;
    }

    int t = (int)threadIdx.x;
    int wave = t >> 6, lane = t & 63;
    int mbase = blockIdx.x * 64 + wave * 16;
    int arow  = mbase + (lane & 15);
    if (arow >= N) arow = N - 1;             // clamped duplicate reads
    int kgrp  = lane >> 4;                   // 0..3

    // A-frag: lane holds Xh[arow][kt*32 + kgrp*8 .. +8]  (16B aligned)
    f16x8 afrag[4];
#pragma unroll
    for (int kt = 0; kt < 4; ++kt) {
        uint4 u = *(const uint4*)(Xh + (size_t)arow * D + kt * 32 + kgrp * 8);
        afrag[kt] = __builtin_bit_cast(f16x8, u);
    }
    f32x4 acc[8];
#pragma unroll
    for (int nt = 0; nt < 8; ++nt) acc[nt] = (f32x4){0.f, 0.f, 0.f, 0.f};
#pragma unroll
    for (int kt = 0; kt < 4; ++kt) {
#pragma unroll
        for (int nt = 0; nt < 8; ++nt) {
            uint4 u = *(const uint4*)(WB + (((kt * 8 + nt) * 64 + lane) * 8));
            f16x8 bfrag = __builtin_bit_cast(f16x8, u);
            acc[nt] = __builtin_amdgcn_mfma_f32_16x16x32_f16(afrag[kt], bfrag, acc[nt], 0, 0, 0);
        }
    }
    // C/D: col = lane&15, row = kgrp*4 + reg   [m89-verified, dtype-indep]
    int r0 = mbase + kgrp * 4;
#pragma unroll
    for (int r = 0; r < 4; ++r) {
        int row = r0 + r;
        if (row < N) {
            float dv = dinv[row];
#pragma unroll
            for (int nt = 0; nt < 8; ++nt)
                Gh[(size_t)row * D + nt * 16 + (lane & 15)] = (_Float16)(dv * acc[nt][r]);
        }
    }
}

// --- agg1: H''_i = dinv_i * relu(dinv_i*(sum_e G'_s + G'_i) + b1), fp16 -----
// 64-lane wave per node (uniform loop); unroll-8 => 8 outstanding 256B gathers.
__global__ __launch_bounds__(256) void agg1_kernel(const unsigned* __restrict__ Gh,
                                                   const int* __restrict__ rowstart,
                                                   const int* __restrict__ colidx,
                                                   const float* __restrict__ dinv,
                                                   const float* __restrict__ b1,
                                                   unsigned* __restrict__ Hh,
                                                   int N, int chunk) {
    int gid  = blockIdx.x * 4 + (threadIdx.x >> 6);
    int lane = threadIdx.x & 63;
    int i0 = gid * chunk, i1 = min(i0 + chunk, N);
    float bx = b1[2 * lane], by = b1[2 * lane + 1];
    for (int i = i0; i < i1; ++i) {
        float di = dinv[i];
        float2 acc = h2f(Gh[(size_t)i * (D / 2) + lane]);   // self term
        int e0 = rowstart[i], e1 = rowstart[i + 1];
        int e = e0;
        for (; e + 7 < e1; e += 8) {
            unsigned u[8];
#pragma unroll
            for (int j = 0; j < 8; ++j)
                u[j] = Gh[(size_t)colidx[e + j] * (D / 2) + lane];
#pragma unroll
            for (int j = 0; j < 8; ++j) {
                float2 v = h2f(u[j]);
                acc.x += v.x;
                acc.y += v.y;
            }
        }
        for (; e + 3 < e1; e += 4) {
            unsigned u[4];
#pragma unroll
            for (int j = 0; j < 4; ++j)
                u[j] = Gh[(size_t)colidx[e + j] * (D / 2) + lane];
#pragma unroll
            for (int j = 0; j < 4; ++j) {
                float2 v = h2f(u[j]);
                acc.x += v.x;
                acc.y += v.y;
            }
        }
        for (; e < e1; ++e) {
            float2 v = h2f(Gh[(size_t)colidx[e] * (D / 2) + lane]);
            acc.x += v.x;
            acc.y += v.y;
        }
        float hx = fmaxf(fmaf(di, acc.x, bx), 0.f) * di;    // H'' = dinv*relu
        float hy = fmaxf(fmaf(di, acc.y, by), 0.f) * di;
        Hh[(size_t)i * (D / 2) + lane] = f2h(hx, hy);
    }
}

// --- agg2 + pool: pool[batch_i] += dinv_i*(sum_e H''_s + H''_i) -------------
__global__ __launch_bounds__(256) void agg2_pool_kernel(const unsigned* __restrict__ Hh,
                                                        const int* __restrict__ rowstart,
                                                        const int* __restrict__ colidx,
                                                        const float* __restrict__ dinv,
                                                        const int* __restrict__ batch,
                                                        float* __restrict__ pool,
                                                        int N, int chunk) {
    int gid  = blockIdx.x * 4 + (threadIdx.x >> 6);
    int lane = threadIdx.x & 63;
    int i0 = gid * chunk, i1 = min(i0 + chunk, N);
    if (i0 >= N) return;

    float2 pa = make_float2(0.f, 0.f);
    int cur = min(max(batch[i0], 0), NGRAPH - 1);
    for (int i = i0; i < i1; ++i) {
        float di = dinv[i];
        float2 a = h2f(Hh[(size_t)i * (D / 2) + lane]);     // self term
        int e0 = rowstart[i], e1 = rowstart[i + 1];
        int e = e0;
        for (; e + 7 < e1; e += 8) {
            unsigned u[8];
#pragma unroll
            for (int j = 0; j < 8; ++j)
                u[j] = Hh[(size_t)colidx[e + j] * (D / 2) + lane];
#pragma unroll
            for (int j = 0; j < 8; ++j) {
                float2 v = h2f(u[j]);
                a.x += v.x;
                a.y += v.y;
            }
        }
        for (; e + 3 < e1; e += 4) {
            unsigned u[4];
#pragma unroll
            for (int j = 0; j < 4; ++j)
                u[j] = Hh[(size_t)colidx[e + j] * (D / 2) + lane];
#pragma unroll
            for (int j = 0; j < 4; ++j) {
                float2 v = h2f(u[j]);
                a.x += v.x;
                a.y += v.y;
            }
        }
        for (; e < e1; ++e) {
            float2 v = h2f(Hh[(size_t)colidx[e] * (D / 2) + lane]);
            a.x += v.x;
            a.y += v.y;
        }
        int b = min(max(batch[i], 0), NGRAPH - 1);
        if (b != cur) {
            atomicAdd(&pool[(size_t)cur * D + 2 * lane], pa.x);
            atomicAdd(&pool[(size_t)cur * D + 2 * lane + 1], pa.y);
            pa = make_float2(0.f, 0.f);
            cur = b;
        }
        pa.x = fmaf(di, a.x, pa.x);
        pa.y = fmaf(di, a.y, pa.y);
    }
    atomicAdd(&pool[(size_t)cur * D + 2 * lane], pa.x);
    atomicAdd(&pool[(size_t)cur * D + 2 * lane + 1], pa.y);
}

// --- Final tiny GEMM: out[g][o] = (pool[g]/cnt_g) . W2[:,o] + b2[o] ---------
__device__ __forceinline__ int lbound(const int* __restrict__ a, int n, int v) {
    int lo = 0, hi = n;
    while (lo < hi) {
        int m = (lo + hi) >> 1;
        if (a[m] < v) lo = m + 1; else hi = m;
    }
    return lo;
}

__global__ void final_gemm_kernel(const float* __restrict__ pool,
                                  const int* __restrict__ batch,
                                  const float* __restrict__ W2,
                                  const float* __restrict__ b2,
                                  float* __restrict__ out, int N) {
    int g = blockIdx.x, o = threadIdx.x;
    int s = lbound(batch, N, g);
    int e = lbound(batch, N, g + 1);
    float inv_cnt = 1.0f / fmaxf((float)(e - s), 1.0f);
    float acc = 0.f;
#pragma unroll 4
    for (int k = 0; k < D; ++k)
        acc = fmaf(pool[g * D + k], W2[k * D + o], acc);
    out[g * D + o] = acc * inv_cnt + b2[o];
}

// ---------------------------------------------------------------------------

extern "C" void kernel_launch(void* const* d_in, const int* in_sizes, int n_in,
                              void* d_out, int out_size, void* d_ws, size_t ws_size,
                              hipStream_t stream) {
    const float* x     = (const float*)d_in[0];
    const int*   ei    = (const int*)  d_in[1];
    const int*   batch = (const int*)  d_in[2];
    const float* W1    = (const float*)d_in[3];
    const float* b1    = (const float*)d_in[4];
    const float* W2    = (const float*)d_in[5];
    const float* b2    = (const float*)d_in[6];
    float* out = (float*)d_out;

    const int N = in_sizes[0] / D;
    const int E = in_sizes[1] / 2;
    const int nblk = (N + SCAN_B - 1) / SCAN_B;   // <=64 for N<=65536

    // workspace carve-up (256B aligned); deg+pool adjacent -> single memset
    char* ws = (char*)d_ws;
    size_t off = 0;
    auto carve = [&](size_t bytes) {
        size_t o = off;
        off = (off + bytes + 255) & ~(size_t)255;
        return o;
    };
    size_t o_deg      = carve((size_t)N * 4);
    size_t o_pool     = carve((size_t)NGRAPH * D * 4);
    size_t zspan      = off;                       // memset [0, zspan)
    size_t o_rowstart = carve((size_t)(N + 1) * 4);
    size_t o_cursor   = carve((size_t)(N + 1) * 4);
    size_t o_dinv     = carve((size_t)N * 4);
    size_t o_colidx   = carve((size_t)E * 4);
    size_t o_bsum     = carve((size_t)64 * 4);
    size_t o_xh       = carve((size_t)N * D * 2);  // fp16 X
    size_t o_wb       = carve((size_t)D * D * 2);  // fp16 W1 (MFMA B order)
    size_t o_gh       = carve((size_t)N * D * 2);  // fp16 G'
    size_t o_hh       = carve((size_t)N * D * 2);  // fp16 H''
    size_t need = off;

    if (ws_size < need) {
        zero_out_kernel<<<(out_size + 255) / 256, 256, 0, stream>>>(out, out_size);
        return;
    }

    int*       deg      = (int*)      (ws + o_deg);
    float*     pool     = (float*)    (ws + o_pool);
    int*       rowstart = (int*)      (ws + o_rowstart);
    int*       cursor   = (int*)      (ws + o_cursor);
    float*     dinv     = (float*)    (ws + o_dinv);
    int*       colidx   = (int*)      (ws + o_colidx);
    int*       bsum     = (int*)      (ws + o_bsum);
    _Float16*  Xh       = (_Float16*) (ws + o_xh);
    _Float16*  WB       = (_Float16*) (ws + o_wb);
    _Float16*  Gh       = (_Float16*) (ws + o_gh);
    _Float16*  Hh       = (_Float16*) (ws + o_hh);

    hipMemsetAsync(ws, 0, zspan, stream);          // deg + pool in one shot

    int eb = (E + 255) / 256;
    int gb = (N + 63) / 64;
    int cb = (N * (D / 4) + 255) / 256;            // X float4-groups

    conv_count_kernel<<<cb + 8 + eb, 256, 0, stream>>>(x, Xh, W1, WB, ei, deg, N, E, cb);
    block_scan_kernel<<<nblk, SCAN_B, 0, stream>>>(deg, rowstart, bsum, dinv, N);
    finalize_scan_kernel<<<nblk, SCAN_B, 0, stream>>>(bsum, rowstart, cursor, N, nblk, E);
    gemm_fill_kernel<<<gb + eb, 256, 0, stream>>>(Xh, WB, dinv, Gh, ei, cursor,
                                                  colidx, N, E, gb);

    int groups = AGG_BLOCKS * 4;
    int chunk  = (N + groups - 1) / groups;
    agg1_kernel<<<AGG_BLOCKS, 256, 0, stream>>>((const unsigned*)Gh, rowstart, colidx,
                                                dinv, b1, (unsigned*)Hh, N, chunk);
    agg2_pool_kernel<<<AGG_BLOCKS, 256, 0, stream>>>((const unsigned*)Hh, rowstart, colidx,
                                                     dinv, batch, pool, N, chunk);
    final_gemm_kernel<<<NGRAPH, D, 0, stream>>>(pool, batch, W2, b2, out, N);
}